// Round 1
// baseline (1360.929 us; speedup 1.0000x reference)
//
#include <hip/hip_runtime.h>
#include <math.h>

#define INDIM 16
#define EMBD 32
#define UDIM 64
#define HIDD 128
#define HEADS 4
#define LAYERS 3

__device__ __forceinline__ float lrelu(float x) { return x > 0.f ? x : 0.2f * x; }

// ---------------- encoder: feat = x@Wf^T + bf ; u = [emb, feat] ----------------
__global__ __launch_bounds__(256) void k_enc_feat(const float* __restrict__ x,
                                                  const float* __restrict__ emb,
                                                  const float* __restrict__ Wf,
                                                  const float* __restrict__ bf,
                                                  float* __restrict__ u, int n) {
    int i = blockIdx.x * 256 + threadIdx.x;
    if (i >= n * EMBD) return;
    int node = i >> 5, j = i & 31;
    const float* xr = x + (size_t)node * INDIM;
    const float* wr = Wf + (size_t)j * INDIM;
    float s = bf[j];
#pragma unroll
    for (int k = 0; k < INDIM; k++) s += xr[k] * wr[k];
    u[(size_t)node * UDIM + EMBD + j] = s;
    u[(size_t)node * UDIM + j] = emb[(size_t)node * EMBD + j];
}

// ---------------- generic fp32 GEMM: C(M,N) = A(M,K) @ W(N,K)^T (+bias)(+relu) ----------------
// BM=128, BN=64, BK=16, 256 threads, 8x4 per thread. Requires N%64==0, K%16==0.
template <bool RELU>
__global__ __launch_bounds__(256) void k_gemm(const float* __restrict__ A,
                                              const float* __restrict__ W,
                                              const float* __restrict__ bias,
                                              float* __restrict__ C,
                                              int M, int N, int K) {
    __shared__ float As[16][128 + 4];
    __shared__ float Bs[16][64 + 4];
    int tid = threadIdx.x;
    int tx = tid & 15, ty = tid >> 4;
    int bm = blockIdx.x * 128, bn = blockIdx.y * 64;
    float acc[8][4] = {};
    for (int kk = 0; kk < K; kk += 16) {
#pragma unroll
        for (int i = 0; i < 8; i++) {
            int idx = tid + i * 256;
            int k = idx & 15, m = idx >> 4;
            int row = bm + m;
            As[k][m] = (row < M) ? A[(size_t)row * K + kk + k] : 0.f;
        }
#pragma unroll
        for (int i = 0; i < 4; i++) {
            int idx = tid + i * 256;
            int k = idx & 15, nn = idx >> 4;
            Bs[k][nn] = W[(size_t)(bn + nn) * K + kk + k];
        }
        __syncthreads();
#pragma unroll
        for (int k = 0; k < 16; k++) {
            float a[8], b[4];
#pragma unroll
            for (int i = 0; i < 8; i++) a[i] = As[k][ty * 8 + i];
#pragma unroll
            for (int j = 0; j < 4; j++) b[j] = Bs[k][tx * 4 + j];
#pragma unroll
            for (int i = 0; i < 8; i++)
#pragma unroll
                for (int j = 0; j < 4; j++) acc[i][j] += a[i] * b[j];
        }
        __syncthreads();
    }
#pragma unroll
    for (int i = 0; i < 8; i++) {
        int row = bm + ty * 8 + i;
        if (row >= M) continue;
#pragma unroll
        for (int j = 0; j < 4; j++) {
            int col = bn + tx * 4 + j;
            float v = acc[i][j] + (bias ? bias[col] : 0.f);
            if (RELU) v = fmaxf(v, 0.f);
            C[(size_t)row * N + col] = v;
        }
    }
}

// ---------------- CSR build ----------------
__global__ __launch_bounds__(256) void k_deg(const int* __restrict__ ei, int* __restrict__ deg,
                                             int E, int tot) {
    int e = blockIdx.x * 256 + threadIdx.x;
    if (e >= tot) return;
    int dst = (e < E) ? ei[E + e] : (e - E);
    atomicAdd(&deg[dst], 1);
}

__global__ __launch_bounds__(1024) void k_scan(const int* __restrict__ deg, int* __restrict__ rowptr,
                                               int* __restrict__ cursor, int n) {
    __shared__ int part[1024];
    int tid = threadIdx.x;
    int chunk = (n + 1023) / 1024;
    int beg = tid * chunk, end = min(beg + chunk, n);
    int s = 0;
    for (int i = beg; i < end; i++) s += deg[i];
    part[tid] = s;
    __syncthreads();
    for (int off = 1; off < 1024; off <<= 1) {
        int v = (tid >= off) ? part[tid - off] : 0;
        __syncthreads();
        part[tid] += v;
        __syncthreads();
    }
    int run = (tid == 0) ? 0 : part[tid - 1];
    for (int i = beg; i < end; i++) {
        rowptr[i] = run;
        cursor[i] = run;
        run += deg[i];
    }
    if (tid == 0) rowptr[n] = part[1023];
}

__global__ __launch_bounds__(256) void k_scatter(const int* __restrict__ ei, int* __restrict__ cursor,
                                                 int* __restrict__ csr_src, int E, int tot) {
    int e = blockIdx.x * 256 + threadIdx.x;
    if (e >= tot) return;
    int src = (e < E) ? ei[e] : (e - E);
    int dst = (e < E) ? ei[E + e] : (e - E);
    int pos = atomicAdd(&cursor[dst], 1);
    csr_src[pos] = src;
}

// ---------------- attention logits: al_s/al_d (N,4) ----------------
__global__ __launch_bounds__(128) void k_al(const float* __restrict__ hp,
                                            const float* __restrict__ a_s,
                                            const float* __restrict__ a_d,
                                            float* __restrict__ al_s, float* __restrict__ al_d) {
    int node = blockIdx.x;
    int c = threadIdx.x;
    const float* row = hp + (size_t)node * (HEADS * HIDD);
    float ps[HEADS], pd[HEADS];
#pragma unroll
    for (int h = 0; h < HEADS; h++) {
        float v = row[h * HIDD + c];
        ps[h] = v * a_s[h * HIDD + c];
        pd[h] = v * a_d[h * HIDD + c];
    }
#pragma unroll
    for (int o = 32; o; o >>= 1)
#pragma unroll
        for (int h = 0; h < HEADS; h++) {
            ps[h] += __shfl_xor(ps[h], o);
            pd[h] += __shfl_xor(pd[h], o);
        }
    __shared__ float red[2][2][HEADS];
    int wid = c >> 6;
    if ((c & 63) == 0)
#pragma unroll
        for (int h = 0; h < HEADS; h++) {
            red[wid][0][h] = ps[h];
            red[wid][1][h] = pd[h];
        }
    __syncthreads();
    if (c < HEADS)
        al_s[(size_t)node * HEADS + c] = red[0][0][c] + red[1][0][c];
    else if (c < 2 * HEADS) {
        int h = c - HEADS;
        al_d[(size_t)node * HEADS + h] = red[0][1][h] + red[1][1][h];
    }
}

// ---------------- per-dst softmax over in-edges; one wave per node ----------------
__global__ __launch_bounds__(256) void k_attn(const int* __restrict__ rowptr,
                                              const int* __restrict__ csr_src,
                                              const float* __restrict__ al_s,
                                              const float* __restrict__ al_d,
                                              float* __restrict__ alpha, int n) {
    int wid = threadIdx.x >> 6;
    int lane = threadIdx.x & 63;
    int node = blockIdx.x * 4 + wid;
    if (node >= n) return;
    int start = rowptr[node], end = rowptr[node + 1];
    const float4* al4 = (const float4*)al_s;
    float4 ad = ((const float4*)al_d)[node];
    float mx[HEADS] = {-3.4e38f, -3.4e38f, -3.4e38f, -3.4e38f};
    for (int j = start + lane; j < end; j += 64) {
        int src = csr_src[j];
        float4 as = al4[src];
        mx[0] = fmaxf(mx[0], lrelu(as.x + ad.x));
        mx[1] = fmaxf(mx[1], lrelu(as.y + ad.y));
        mx[2] = fmaxf(mx[2], lrelu(as.z + ad.z));
        mx[3] = fmaxf(mx[3], lrelu(as.w + ad.w));
    }
#pragma unroll
    for (int o = 32; o; o >>= 1)
#pragma unroll
        for (int h = 0; h < HEADS; h++) mx[h] = fmaxf(mx[h], __shfl_xor(mx[h], o));
    float s[HEADS] = {0.f, 0.f, 0.f, 0.f};
    for (int j = start + lane; j < end; j += 64) {
        int src = csr_src[j];
        float4 as = al4[src];
        s[0] += expf(lrelu(as.x + ad.x) - mx[0]);
        s[1] += expf(lrelu(as.y + ad.y) - mx[1]);
        s[2] += expf(lrelu(as.z + ad.z) - mx[2]);
        s[3] += expf(lrelu(as.w + ad.w) - mx[3]);
    }
#pragma unroll
    for (int o = 32; o; o >>= 1)
#pragma unroll
        for (int h = 0; h < HEADS; h++) s[h] += __shfl_xor(s[h], o);
    float inv[HEADS];
#pragma unroll
    for (int h = 0; h < HEADS; h++) inv[h] = 1.f / (s[h] + 1e-16f);
    for (int j = start + lane; j < end; j += 64) {
        int src = csr_src[j];
        float4 as = al4[src];
        float4 a;
        a.x = expf(lrelu(as.x + ad.x) - mx[0]) * inv[0];
        a.y = expf(lrelu(as.y + ad.y) - mx[1]) * inv[1];
        a.z = expf(lrelu(as.z + ad.z) - mx[2]) * inv[2];
        a.w = expf(lrelu(as.w + ad.w) - mx[3]) * inv[3];
        ((float4*)alpha)[j] = a;
    }
}

// ---------------- aggregation: agg[n][c] = 0.25 * sum_e sum_h alpha*hp[src][h][c] ----------------
__global__ __launch_bounds__(128) void k_agg(const int* __restrict__ rowptr,
                                             const int* __restrict__ csr_src,
                                             const float* __restrict__ alpha,
                                             const float* __restrict__ hp,
                                             float* __restrict__ agg) {
    int node = blockIdx.x;
    int c = threadIdx.x;
    int start = rowptr[node], end = rowptr[node + 1];
    float acc = 0.f;
    for (int j = start; j < end; j++) {
        int src = csr_src[j];
        float4 a = ((const float4*)alpha)[j];
        const float* row = hp + (size_t)src * (HEADS * HIDD);
        acc += a.x * row[c] + a.y * row[HIDD + c] + a.z * row[2 * HIDD + c] + a.w * row[3 * HIDD + c];
    }
    agg[(size_t)node * HIDD + c] = 0.25f * acc;
}

// ---------------- BN stats ----------------
__global__ __launch_bounds__(256) void k_bn_reduce(const float* __restrict__ agg,
                                                   float* __restrict__ sums, int n) {
    int c = threadIdx.x & 127;
    int half = threadIdx.x >> 7;
    float s = 0.f, q = 0.f;
    for (int r = blockIdx.x * 2 + half; r < n; r += gridDim.x * 2) {
        float v = agg[(size_t)r * HIDD + c];
        s += v;
        q += v * v;
    }
    __shared__ float ls[256], lq[256];
    ls[threadIdx.x] = s;
    lq[threadIdx.x] = q;
    __syncthreads();
    if (half == 0) {
        atomicAdd(&sums[c], ls[c] + ls[128 + c]);
        atomicAdd(&sums[128 + c], lq[c] + lq[128 + c]);
    }
}

__global__ __launch_bounds__(128) void k_bn_final(const float* __restrict__ sums,
                                                  const float* __restrict__ gamma,
                                                  const float* __restrict__ beta,
                                                  float* __restrict__ scale,
                                                  float* __restrict__ shift, int n) {
    int c = threadIdx.x;
    float mu = sums[c] / (float)n;
    float var = sums[128 + c] / (float)n - mu * mu;
    float sc = gamma[c] * rsqrtf(var + 1e-5f);
    scale[c] = sc;
    shift[c] = beta[c] - mu * sc;
}

// ---------------- BN apply + relu + residual (in place on h) ----------------
__global__ __launch_bounds__(256) void k_apply(const float* __restrict__ agg,
                                               const float* __restrict__ scale,
                                               const float* __restrict__ shift,
                                               float* __restrict__ h, int total) {
    int i = blockIdx.x * 256 + threadIdx.x;
    if (i >= total) return;
    int c = i & 127;
    float v = fmaxf(agg[i] * scale[c] + shift[c], 0.f);
    h[i] = v + h[i];
}

// ---------------- output head ----------------
__global__ __launch_bounds__(256) void k_out(const float* __restrict__ h,
                                             const float* __restrict__ Wout,
                                             const float* __restrict__ bout,
                                             float* __restrict__ out, int n) {
    int node = (blockIdx.x * 256 + threadIdx.x) >> 6;
    int lane = threadIdx.x & 63;
    if (node >= n) return;
    const float* row = h + (size_t)node * HIDD;
    float p = row[lane] * Wout[lane] + row[64 + lane] * Wout[64 + lane];
#pragma unroll
    for (int o = 32; o; o >>= 1) p += __shfl_xor(p, o);
    if (lane == 0) {
        float v = p + bout[0];
        out[node] = fminf(fmaxf(v, -10.f), 10.f);
    }
}

extern "C" void kernel_launch(void* const* d_in, const int* in_sizes, int n_in,
                              void* d_out, int out_size, void* d_ws, size_t ws_size,
                              hipStream_t stream) {
    const float* x = (const float*)d_in[0];
    const int* ei = (const int*)d_in[1];
    const float* emb = (const float*)d_in[2];
    const float* Wf = (const float*)d_in[3];
    const float* bf = (const float*)d_in[4];
    const float* Wc = (const float*)d_in[5];
    const float* bc = (const float*)d_in[6];
    const float* Wl = (const float*)d_in[7];
    const float* a_src = (const float*)d_in[8];
    const float* a_dst = (const float*)d_in[9];
    // d_in[10] = bl : mathematically cancels in BN (mean subtraction) -> skipped
    const float* gamma = (const float*)d_in[11];
    const float* beta = (const float*)d_in[12];
    const float* Wout = (const float*)d_in[13];
    const float* bout = (const float*)d_in[14];
    float* out = (float*)d_out;

    int n = in_sizes[0] / INDIM;       // 50000
    int E = in_sizes[1] / 2;           // 400000
    int tot = E + n;                   // edges incl. self loops

    // workspace layout
    size_t off = 0;
    auto alloc = [&](size_t bytes) {
        void* p = (char*)d_ws + off;
        off = (off + bytes + 255) & ~(size_t)255;
        return p;
    };
    float* u = (float*)alloc((size_t)n * UDIM * 4);
    float* h = (float*)alloc((size_t)n * HIDD * 4);
    float* agg = (float*)alloc((size_t)n * HIDD * 4);
    float* hp = (float*)alloc((size_t)n * HEADS * HIDD * 4);
    float* al_s = (float*)alloc((size_t)n * HEADS * 4);
    float* al_d = (float*)alloc((size_t)n * HEADS * 4);
    float* alpha = (float*)alloc((size_t)tot * HEADS * 4);
    int* deg = (int*)alloc((size_t)n * 4);
    int* rowptr = (int*)alloc(((size_t)n + 1) * 4);
    int* cursor = (int*)alloc((size_t)n * 4);
    int* csr_src = (int*)alloc((size_t)tot * 4);
    float* bnsums = (float*)alloc(LAYERS * 256 * 4);
    float* scale = (float*)alloc(128 * 4);
    float* shift = (float*)alloc(128 * 4);
    (void)ws_size;

    hipMemsetAsync(deg, 0, (size_t)n * 4, stream);
    hipMemsetAsync(bnsums, 0, LAYERS * 256 * 4, stream);

    // encoder
    k_enc_feat<<<(n * EMBD + 255) / 256, 256, 0, stream>>>(x, emb, Wf, bf, u, n);
    {
        dim3 g((n + 127) / 128, HIDD / 64);
        k_gemm<true><<<g, 256, 0, stream>>>(u, Wc, bc, h, n, HIDD, UDIM);
    }

    // CSR build
    k_deg<<<(tot + 255) / 256, 256, 0, stream>>>(ei, deg, E, tot);
    k_scan<<<1, 1024, 0, stream>>>(deg, rowptr, cursor, n);
    k_scatter<<<(tot + 255) / 256, 256, 0, stream>>>(ei, cursor, csr_src, E, tot);

    for (int l = 0; l < LAYERS; l++) {
        const float* W = Wl + (size_t)l * (HEADS * HIDD) * HIDD;
        {
            dim3 g((n + 127) / 128, (HEADS * HIDD) / 64);
            k_gemm<false><<<g, 256, 0, stream>>>(h, W, nullptr, hp, n, HEADS * HIDD, HIDD);
        }
        k_al<<<n, 128, 0, stream>>>(hp, a_src + (size_t)l * HEADS * HIDD,
                                    a_dst + (size_t)l * HEADS * HIDD, al_s, al_d);
        k_attn<<<(n + 3) / 4, 256, 0, stream>>>(rowptr, csr_src, al_s, al_d, alpha, n);
        k_agg<<<n, 128, 0, stream>>>(rowptr, csr_src, alpha, hp, agg);
        k_bn_reduce<<<256, 256, 0, stream>>>(agg, bnsums + l * 256, n);
        k_bn_final<<<1, 128, 0, stream>>>(bnsums + l * 256, gamma + l * HIDD, beta + l * HIDD,
                                          scale, shift, n);
        k_apply<<<(n * HIDD + 255) / 256, 256, 0, stream>>>(agg, scale, shift, h, n * HIDD);
    }

    k_out<<<(n * 64 + 255) / 256, 256, 0, stream>>>(h, Wout, bout, out, n);
}

// Round 2
// 788.609 us; speedup vs baseline: 1.7257x; 1.7257x over previous
//
#include <hip/hip_runtime.h>
#include <hip/hip_bf16.h>
#include <math.h>

#define INDIM 16
#define EMBD 32
#define UDIM 64
#define HIDD 128
#define HEADS 4
#define LAYERS 3
#define MPAD 50048  // 391 * 128

typedef short v8s __attribute__((ext_vector_type(8)));
typedef float v4f __attribute__((ext_vector_type(4)));

__device__ __forceinline__ float lrelu(float x) { return x > 0.f ? x : 0.2f * x; }
__device__ __forceinline__ float bf2f(unsigned int bits16) {
    unsigned int u = bits16 << 16;
    return __builtin_bit_cast(float, u);
}
__device__ __forceinline__ unsigned short f2bf(float f) {
    unsigned int u = __builtin_bit_cast(unsigned int, f);
    unsigned int lsb = (u >> 16) & 1;
    u += 0x7fff + lsb;  // round to nearest even
    return (unsigned short)(u >> 16);
}

// ---------------- encoder features: u = [emb, x@Wf^T + bf] in bf16 ----------------
__global__ __launch_bounds__(256) void k_enc(const float* __restrict__ x,
                                             const float* __restrict__ emb,
                                             const float* __restrict__ Wf,
                                             const float* __restrict__ bf,
                                             unsigned short* __restrict__ u, int n) {
    int i = blockIdx.x * 256 + threadIdx.x;
    if (i >= n * EMBD) return;
    int node = i >> 5, j = i & 31;
    const float* xr = x + (size_t)node * INDIM;
    const float* wr = Wf + (size_t)j * INDIM;
    float s = bf[j];
#pragma unroll
    for (int k = 0; k < INDIM; k++) s += xr[k] * wr[k];
    u[(size_t)node * UDIM + EMBD + j] = f2bf(s);
    u[(size_t)node * UDIM + j] = f2bf(emb[(size_t)node * EMBD + j]);
}

// ---------------- weight precompute ----------------
// Vb[l][c][h*128+k] = Wl[l][h*128+c][k]  (bf16)
__global__ __launch_bounds__(256) void k_prep_v(const float* __restrict__ Wl,
                                                unsigned short* __restrict__ Vb) {
    int i = blockIdx.x * 256 + threadIdx.x;
    if (i >= LAYERS * HIDD * 512) return;
    int l = i >> 16;
    int rem = i & 65535;
    int c = rem >> 9;
    int f = rem & 511;
    int h = f >> 7, k = f & 127;
    Vb[i] = f2bf(Wl[(size_t)l * 512 * HIDD + (size_t)(h * HIDD + c) * HIDD + k]);
}

// ws[l][h][k] = sum_c a_s[l,h,c] * Wl[l][h*128+c][k]   (and wd for a_dst)
__global__ __launch_bounds__(256) void k_prep_a(const float* __restrict__ Wl,
                                                const float* __restrict__ a_s,
                                                const float* __restrict__ a_d,
                                                float* __restrict__ ws, float* __restrict__ wd) {
    int i = blockIdx.x * 256 + threadIdx.x;
    if (i >= LAYERS * HEADS * HIDD) return;
    int l = i >> 9, h = (i >> 7) & 3, k = i & 127;
    const float* W = Wl + (size_t)l * 512 * HIDD;
    const float* as = a_s + l * 512 + h * HIDD;
    const float* ad = a_d + l * 512 + h * HIDD;
    float ss = 0.f, sd = 0.f;
    for (int c = 0; c < HIDD; c++) {
        float w = W[(size_t)(h * HIDD + c) * HIDD + k];
        ss += as[c] * w;
        sd += ad[c] * w;
    }
    ws[i] = ss;
    wd[i] = sd;
}

__global__ __launch_bounds__(256) void k_prep_wc(const float* __restrict__ Wc,
                                                 unsigned short* __restrict__ Wcb) {
    int i = blockIdx.x * 256 + threadIdx.x;
    if (i < HIDD * UDIM) Wcb[i] = f2bf(Wc[i]);
}

// ---------------- bf16 MFMA GEMM: O(M,128) = A(M,K) @ B(128,K)^T ----------------
// 256 threads = 4 waves (2x2), wave tile 64x64, 16x16x32 MFMA, LDS-free.
// EPI 0: +bias, relu, write fp32 O and bf16 Ob.  EPI 1: *0.25, write fp32 O.
template <int K, int EPI>
__global__ __launch_bounds__(256) void k_gemm(const unsigned short* __restrict__ A,
                                              const unsigned short* __restrict__ B,
                                              const float* __restrict__ bias,
                                              float* __restrict__ O,
                                              unsigned short* __restrict__ Ob, int M) {
    int tid = threadIdx.x;
    int lane = tid & 63, wid = tid >> 6;
    int wm = wid >> 1, wn = wid & 1;
    int bm = blockIdx.x * 128;
    int lr = lane & 15, lk = lane >> 4;
    v4f acc[4][4] = {};
    const unsigned short* Abase = A + (size_t)(bm + wm * 64 + lr) * K + lk * 8;
    const unsigned short* Bbase = B + (size_t)(wn * 64 + lr) * K + lk * 8;
#pragma unroll
    for (int kk = 0; kk < K / 32; kk++) {
        v8s a[4], b[4];
#pragma unroll
        for (int f = 0; f < 4; f++) {
            a[f] = *(const v8s*)(Abase + (size_t)(f * 16) * K + kk * 32);
            b[f] = *(const v8s*)(Bbase + (size_t)(f * 16) * K + kk * 32);
        }
#pragma unroll
        for (int i = 0; i < 4; i++)
#pragma unroll
            for (int j = 0; j < 4; j++)
                acc[i][j] = __builtin_amdgcn_mfma_f32_16x16x32_bf16(a[i], b[j], acc[i][j], 0, 0, 0);
    }
#pragma unroll
    for (int i = 0; i < 4; i++) {
#pragma unroll
        for (int r = 0; r < 4; r++) {
            int row = bm + wm * 64 + i * 16 + lk * 4 + r;
            if (row >= M) continue;
#pragma unroll
            for (int j = 0; j < 4; j++) {
                int col = wn * 64 + j * 16 + lr;
                float v = acc[i][j][r];
                if (EPI == 0) {
                    v = fmaxf(v + bias[col], 0.f);
                    O[(size_t)row * HIDD + col] = v;
                    Ob[(size_t)row * HIDD + col] = f2bf(v);
                } else {
                    O[(size_t)row * HIDD + col] = v * 0.25f;
                }
            }
        }
    }
}

// ---------------- CSR build ----------------
__global__ __launch_bounds__(256) void k_deg(const int* __restrict__ ei, int* __restrict__ deg,
                                             int E, int tot) {
    int e = blockIdx.x * 256 + threadIdx.x;
    if (e >= tot) return;
    int dst = (e < E) ? ei[E + e] : (e - E);
    atomicAdd(&deg[dst], 1);
}

__global__ __launch_bounds__(1024) void k_scan(const int* __restrict__ deg, int* __restrict__ rowptr,
                                               int* __restrict__ cursor, int n) {
    __shared__ int part[1024];
    int tid = threadIdx.x;
    int chunk = (n + 1023) / 1024;
    int beg = tid * chunk, end = min(beg + chunk, n);
    int s = 0;
    for (int i = beg; i < end; i++) s += deg[i];
    part[tid] = s;
    __syncthreads();
    for (int off = 1; off < 1024; off <<= 1) {
        int v = (tid >= off) ? part[tid - off] : 0;
        __syncthreads();
        part[tid] += v;
        __syncthreads();
    }
    int run = (tid == 0) ? 0 : part[tid - 1];
    for (int i = beg; i < end; i++) {
        rowptr[i] = run;
        cursor[i] = run;
        run += deg[i];
    }
    if (tid == 0) rowptr[n] = part[1023];
}

__global__ __launch_bounds__(256) void k_scatter(const int* __restrict__ ei, int* __restrict__ cursor,
                                                 int* __restrict__ csr_src, int E, int tot) {
    int e = blockIdx.x * 256 + threadIdx.x;
    if (e >= tot) return;
    int src = (e < E) ? ei[e] : (e - E);
    int dst = (e < E) ? ei[E + e] : (e - E);
    int pos = atomicAdd(&cursor[dst], 1);
    csr_src[pos] = src;
}

// ---------------- attention logits from h directly: al = h . ws ----------------
__global__ __launch_bounds__(256) void k_al(const unsigned short* __restrict__ hb,
                                            const float* __restrict__ ws,
                                            const float* __restrict__ wd,
                                            float* __restrict__ al_s, float* __restrict__ al_d,
                                            int n) {
    int wid = threadIdx.x >> 6, lane = threadIdx.x & 63;
    int node = blockIdx.x * 4 + wid;
    if (node >= n) return;
    unsigned int u = ((const unsigned int*)hb)[(size_t)node * 64 + lane];
    float h0 = bf2f(u & 0xffff), h1 = bf2f(u >> 16);
    float s[8];
#pragma unroll
    for (int h = 0; h < 4; h++) {
        float2 w1 = *(const float2*)(ws + h * HIDD + 2 * lane);
        float2 w2 = *(const float2*)(wd + h * HIDD + 2 * lane);
        s[h] = h0 * w1.x + h1 * w1.y;
        s[4 + h] = h0 * w2.x + h1 * w2.y;
    }
#pragma unroll
    for (int o = 32; o; o >>= 1)
#pragma unroll
        for (int q = 0; q < 8; q++) s[q] += __shfl_xor(s[q], o);
    if (lane == 0) {
        *(float4*)(al_s + (size_t)node * 4) = make_float4(s[0], s[1], s[2], s[3]);
        *(float4*)(al_d + (size_t)node * 4) = make_float4(s[4], s[5], s[6], s[7]);
    }
}

// ---------------- per-dst softmax over in-edges; one wave per node ----------------
__global__ __launch_bounds__(256) void k_attn(const int* __restrict__ rowptr,
                                              const int* __restrict__ csr_src,
                                              const float* __restrict__ al_s,
                                              const float* __restrict__ al_d,
                                              float* __restrict__ alpha, int n) {
    int wid = threadIdx.x >> 6;
    int lane = threadIdx.x & 63;
    int node = blockIdx.x * 4 + wid;
    if (node >= n) return;
    int start = rowptr[node], end = rowptr[node + 1];
    const float4* al4 = (const float4*)al_s;
    float4 ad = ((const float4*)al_d)[node];
    float mx[HEADS] = {-3.4e38f, -3.4e38f, -3.4e38f, -3.4e38f};
    for (int j = start + lane; j < end; j += 64) {
        int src = csr_src[j];
        float4 as = al4[src];
        mx[0] = fmaxf(mx[0], lrelu(as.x + ad.x));
        mx[1] = fmaxf(mx[1], lrelu(as.y + ad.y));
        mx[2] = fmaxf(mx[2], lrelu(as.z + ad.z));
        mx[3] = fmaxf(mx[3], lrelu(as.w + ad.w));
    }
#pragma unroll
    for (int o = 32; o; o >>= 1)
#pragma unroll
        for (int h = 0; h < HEADS; h++) mx[h] = fmaxf(mx[h], __shfl_xor(mx[h], o));
    float s[HEADS] = {0.f, 0.f, 0.f, 0.f};
    for (int j = start + lane; j < end; j += 64) {
        int src = csr_src[j];
        float4 as = al4[src];
        s[0] += expf(lrelu(as.x + ad.x) - mx[0]);
        s[1] += expf(lrelu(as.y + ad.y) - mx[1]);
        s[2] += expf(lrelu(as.z + ad.z) - mx[2]);
        s[3] += expf(lrelu(as.w + ad.w) - mx[3]);
    }
#pragma unroll
    for (int o = 32; o; o >>= 1)
#pragma unroll
        for (int h = 0; h < HEADS; h++) s[h] += __shfl_xor(s[h], o);
    float inv[HEADS];
#pragma unroll
    for (int h = 0; h < HEADS; h++) inv[h] = 1.f / (s[h] + 1e-16f);
    for (int j = start + lane; j < end; j += 64) {
        int src = csr_src[j];
        float4 as = al4[src];
        float4 a;
        a.x = expf(lrelu(as.x + ad.x) - mx[0]) * inv[0];
        a.y = expf(lrelu(as.y + ad.y) - mx[1]) * inv[1];
        a.z = expf(lrelu(as.z + ad.z) - mx[2]) * inv[2];
        a.w = expf(lrelu(as.w + ad.w) - mx[3]) * inv[3];
        ((float4*)alpha)[j] = a;
    }
}

// ---------------- gather: G[n][h*128+k] = sum_e alpha[e,h] * h[src,k]  (bf16 out) ----------------
__global__ __launch_bounds__(256) void k_gather(const int* __restrict__ rowptr,
                                                const int* __restrict__ csr_src,
                                                const float* __restrict__ alpha,
                                                const unsigned short* __restrict__ hb,
                                                unsigned short* __restrict__ g, int n) {
    int wid = threadIdx.x >> 6, lane = threadIdx.x & 63;
    int node = blockIdx.x * 4 + wid;
    if (node >= n) return;
    int start = rowptr[node], end = rowptr[node + 1];
    float acc[4][2] = {};
    const unsigned int* h2 = (const unsigned int*)hb;
    for (int j = start; j < end; j++) {
        int src = csr_src[j];
        float4 a = ((const float4*)alpha)[j];
        unsigned int u = h2[(size_t)src * 64 + lane];
        float x0 = bf2f(u & 0xffff), x1 = bf2f(u >> 16);
        acc[0][0] += a.x * x0; acc[0][1] += a.x * x1;
        acc[1][0] += a.y * x0; acc[1][1] += a.y * x1;
        acc[2][0] += a.z * x0; acc[2][1] += a.z * x1;
        acc[3][0] += a.w * x0; acc[3][1] += a.w * x1;
    }
    unsigned int* g2 = (unsigned int*)g;
#pragma unroll
    for (int h = 0; h < 4; h++) {
        unsigned int p = (unsigned int)f2bf(acc[h][0]) | ((unsigned int)f2bf(acc[h][1]) << 16);
        g2[(size_t)node * 256 + h * 64 + lane] = p;
    }
}

// ---------------- BN stats ----------------
__global__ __launch_bounds__(256) void k_bn_reduce(const float* __restrict__ agg,
                                                   float* __restrict__ sums, int n) {
    int c = threadIdx.x & 127;
    int half = threadIdx.x >> 7;
    float s = 0.f, q = 0.f;
    for (int r = blockIdx.x * 2 + half; r < n; r += gridDim.x * 2) {
        float v = agg[(size_t)r * HIDD + c];
        s += v;
        q += v * v;
    }
    __shared__ float ls[256], lq[256];
    ls[threadIdx.x] = s;
    lq[threadIdx.x] = q;
    __syncthreads();
    if (half == 0) {
        atomicAdd(&sums[c], ls[c] + ls[128 + c]);
        atomicAdd(&sums[128 + c], lq[c] + lq[128 + c]);
    }
}

__global__ __launch_bounds__(128) void k_bn_final(const float* __restrict__ sums,
                                                  const float* __restrict__ gamma,
                                                  const float* __restrict__ beta,
                                                  float* __restrict__ scale,
                                                  float* __restrict__ shift, int n) {
    int c = threadIdx.x;
    float mu = sums[c] / (float)n;
    float var = sums[128 + c] / (float)n - mu * mu;
    float sc = gamma[c] * rsqrtf(var + 1e-5f);
    scale[c] = sc;
    shift[c] = beta[c] - mu * sc;
}

// ---------------- BN apply + relu + residual; update h (fp32) and hb (bf16) ----------------
__global__ __launch_bounds__(256) void k_apply(const float* __restrict__ agg,
                                               const float* __restrict__ scale,
                                               const float* __restrict__ shift,
                                               float* __restrict__ h,
                                               unsigned short* __restrict__ hb, int total) {
    int i = blockIdx.x * 256 + threadIdx.x;
    if (i >= total) return;
    int c = i & 127;
    float v = fmaxf(agg[i] * scale[c] + shift[c], 0.f) + h[i];
    h[i] = v;
    hb[i] = f2bf(v);
}

// ---------------- output head ----------------
__global__ __launch_bounds__(256) void k_out(const float* __restrict__ h,
                                             const float* __restrict__ Wout,
                                             const float* __restrict__ bout,
                                             float* __restrict__ out, int n) {
    int node = (blockIdx.x * 256 + threadIdx.x) >> 6;
    int lane = threadIdx.x & 63;
    if (node >= n) return;
    const float* row = h + (size_t)node * HIDD;
    float p = row[lane] * Wout[lane] + row[64 + lane] * Wout[64 + lane];
#pragma unroll
    for (int o = 32; o; o >>= 1) p += __shfl_xor(p, o);
    if (lane == 0) {
        float v = p + bout[0];
        out[node] = fminf(fmaxf(v, -10.f), 10.f);
    }
}

extern "C" void kernel_launch(void* const* d_in, const int* in_sizes, int n_in,
                              void* d_out, int out_size, void* d_ws, size_t ws_size,
                              hipStream_t stream) {
    const float* x = (const float*)d_in[0];
    const int* ei = (const int*)d_in[1];
    const float* emb = (const float*)d_in[2];
    const float* Wf = (const float*)d_in[3];
    const float* bf = (const float*)d_in[4];
    const float* Wc = (const float*)d_in[5];
    const float* bc = (const float*)d_in[6];
    const float* Wl = (const float*)d_in[7];
    const float* a_src = (const float*)d_in[8];
    const float* a_dst = (const float*)d_in[9];
    // d_in[10] = bl : cancels in BN mean subtraction
    const float* gamma = (const float*)d_in[11];
    const float* beta = (const float*)d_in[12];
    const float* Wout = (const float*)d_in[13];
    const float* bout = (const float*)d_in[14];
    float* out = (float*)d_out;

    int n = in_sizes[0] / INDIM;  // 50000
    int E = in_sizes[1] / 2;      // 400000
    int tot = E + n;

    size_t off = 0;
    auto alloc = [&](size_t bytes) {
        void* p = (char*)d_ws + off;
        off = (off + bytes + 255) & ~(size_t)255;
        return p;
    };
    unsigned short* u = (unsigned short*)alloc((size_t)MPAD * UDIM * 2);
    float* h = (float*)alloc((size_t)MPAD * HIDD * 4);
    unsigned short* hb = (unsigned short*)alloc((size_t)MPAD * HIDD * 2);
    unsigned short* g = (unsigned short*)alloc((size_t)MPAD * 512 * 2);
    float* agg = (float*)alloc((size_t)MPAD * HIDD * 4);
    float* al_s = (float*)alloc((size_t)n * HEADS * 4);
    float* al_d = (float*)alloc((size_t)n * HEADS * 4);
    float* alpha = (float*)alloc((size_t)tot * HEADS * 4);
    int* deg = (int*)alloc((size_t)n * 4);
    int* rowptr = (int*)alloc(((size_t)n + 1) * 4);
    int* cursor = (int*)alloc((size_t)n * 4);
    int* csr_src = (int*)alloc((size_t)tot * 4);
    unsigned short* Vb = (unsigned short*)alloc((size_t)LAYERS * HIDD * 512 * 2);
    unsigned short* Wcb = (unsigned short*)alloc((size_t)HIDD * UDIM * 2);
    float* ws = (float*)alloc((size_t)LAYERS * HEADS * HIDD * 4);
    float* wd = (float*)alloc((size_t)LAYERS * HEADS * HIDD * 4);
    float* bnsums = (float*)alloc(LAYERS * 256 * 4);
    float* scale = (float*)alloc(128 * 4);
    float* shift = (float*)alloc(128 * 4);
    (void)ws_size;

    hipMemsetAsync(deg, 0, (size_t)n * 4, stream);
    hipMemsetAsync(bnsums, 0, LAYERS * 256 * 4, stream);
    if (n < MPAD) {  // zero pad rows of GEMM inputs
        hipMemsetAsync(u + (size_t)n * UDIM, 0, (size_t)(MPAD - n) * UDIM * 2, stream);
        hipMemsetAsync(g + (size_t)n * 512, 0, (size_t)(MPAD - n) * 512 * 2, stream);
    }

    // weight precompute
    k_prep_v<<<(LAYERS * HIDD * 512 + 255) / 256, 256, 0, stream>>>(Wl, Vb);
    k_prep_a<<<(LAYERS * HEADS * HIDD + 255) / 256, 256, 0, stream>>>(Wl, a_src, a_dst, ws, wd);
    k_prep_wc<<<(HIDD * UDIM + 255) / 256, 256, 0, stream>>>(Wc, Wcb);

    // encoder
    k_enc<<<(n * EMBD + 255) / 256, 256, 0, stream>>>(x, emb, Wf, bf, u, n);
    k_gemm<UDIM, 0><<<MPAD / 128, 256, 0, stream>>>(u, Wcb, bc, h, hb, n);

    // CSR build
    k_deg<<<(tot + 255) / 256, 256, 0, stream>>>(ei, deg, E, tot);
    k_scan<<<1, 1024, 0, stream>>>(deg, rowptr, cursor, n);
    k_scatter<<<(tot + 255) / 256, 256, 0, stream>>>(ei, cursor, csr_src, E, tot);

    for (int l = 0; l < LAYERS; l++) {
        k_al<<<(n + 3) / 4, 256, 0, stream>>>(hb, ws + (size_t)l * 512, wd + (size_t)l * 512,
                                              al_s, al_d, n);
        k_attn<<<(n + 3) / 4, 256, 0, stream>>>(rowptr, csr_src, al_s, al_d, alpha, n);
        k_gather<<<(n + 3) / 4, 256, 0, stream>>>(rowptr, csr_src, alpha, hb, g, n);
        k_gemm<512, 1><<<MPAD / 128, 256, 0, stream>>>(g, Vb + (size_t)l * HIDD * 512, nullptr,
                                                       agg, nullptr, n);
        k_bn_reduce<<<256, 256, 0, stream>>>(agg, bnsums + l * 256, n);
        k_bn_final<<<1, 128, 0, stream>>>(bnsums + l * 256, gamma + l * HIDD, beta + l * HIDD,
                                          scale, shift, n);
        k_apply<<<(n * HIDD + 255) / 256, 256, 0, stream>>>(agg, scale, shift, h, hb, n * HIDD);
    }

    k_out<<<(n * 64 + 255) / 256, 256, 0, stream>>>(h, Wout, bout, out, n);
}

// Round 3
// 486.332 us; speedup vs baseline: 2.7984x; 1.6215x over previous
//
#include <hip/hip_runtime.h>
#include <hip/hip_bf16.h>
#include <math.h>

#define INDIM 16
#define EMBD 32
#define UDIM 64
#define HIDD 128
#define HEADS 4
#define LAYERS 3
#define MPAD 50048  // 391 * 128

typedef short v8s __attribute__((ext_vector_type(8)));
typedef float v4f __attribute__((ext_vector_type(4)));

__device__ __forceinline__ float lrelu(float x) { return x > 0.f ? x : 0.2f * x; }
__device__ __forceinline__ float bf2f(unsigned int bits16) {
    unsigned int u = bits16 << 16;
    return __builtin_bit_cast(float, u);
}
__device__ __forceinline__ unsigned short f2bf(float f) {
    unsigned int u = __builtin_bit_cast(unsigned int, f);
    unsigned int lsb = (u >> 16) & 1;
    u += 0x7fff + lsb;  // round to nearest even
    return (unsigned short)(u >> 16);
}

// ---------------- encoder features: u = [emb, x@Wf^T + bf] in bf16 ----------------
__global__ __launch_bounds__(256) void k_enc(const float* __restrict__ x,
                                             const float* __restrict__ emb,
                                             const float* __restrict__ Wf,
                                             const float* __restrict__ bf,
                                             unsigned short* __restrict__ u, int n) {
    int i = blockIdx.x * 256 + threadIdx.x;
    if (i >= n * EMBD) return;
    int node = i >> 5, j = i & 31;
    const float* xr = x + (size_t)node * INDIM;
    const float* wr = Wf + (size_t)j * INDIM;
    float s = bf[j];
#pragma unroll
    for (int k = 0; k < INDIM; k++) s += xr[k] * wr[k];
    u[(size_t)node * UDIM + EMBD + j] = f2bf(s);
    u[(size_t)node * UDIM + j] = f2bf(emb[(size_t)node * EMBD + j]);
}

// ---------------- weight precompute ----------------
__global__ __launch_bounds__(256) void k_prep_v(const float* __restrict__ Wl,
                                                unsigned short* __restrict__ Vb) {
    int i = blockIdx.x * 256 + threadIdx.x;
    if (i >= LAYERS * HIDD * 512) return;
    int l = i >> 16;
    int rem = i & 65535;
    int c = rem >> 9;
    int f = rem & 511;
    int h = f >> 7, k = f & 127;
    Vb[i] = f2bf(Wl[(size_t)l * 512 * HIDD + (size_t)(h * HIDD + c) * HIDD + k]);
}

// ws[l][h][k] = sum_c a_s[l,h,c] * Wl[l][h*128+c][k]   (and wd for a_dst)
__global__ __launch_bounds__(256) void k_prep_a(const float* __restrict__ Wl,
                                                const float* __restrict__ a_s,
                                                const float* __restrict__ a_d,
                                                float* __restrict__ ws, float* __restrict__ wd) {
    int i = blockIdx.x * 256 + threadIdx.x;
    if (i >= LAYERS * HEADS * HIDD) return;
    int l = i >> 9, h = (i >> 7) & 3, k = i & 127;
    const float* W = Wl + (size_t)l * 512 * HIDD;
    const float* as = a_s + l * 512 + h * HIDD;
    const float* ad = a_d + l * 512 + h * HIDD;
    float ss = 0.f, sd = 0.f;
    for (int c = 0; c < HIDD; c++) {
        float w = W[(size_t)(h * HIDD + c) * HIDD + k];
        ss += as[c] * w;
        sd += ad[c] * w;
    }
    ws[i] = ss;
    wd[i] = sd;
}

__global__ __launch_bounds__(256) void k_prep_wc(const float* __restrict__ Wc,
                                                 unsigned short* __restrict__ Wcb) {
    int i = blockIdx.x * 256 + threadIdx.x;
    if (i < HIDD * UDIM) Wcb[i] = f2bf(Wc[i]);
}

// ---------------- bf16 MFMA GEMM: O(M,128) = A(M,K) @ B(128,K)^T ----------------
// EPI 0: +bias, relu, write fp32 O and bf16 Ob (rows<M).
// EPI 1: write fp32 O (all MPAD rows) + accumulate BN sums (sum, sumsq) into bns.
template <int K, int EPI>
__global__ __launch_bounds__(256) void k_gemm(const unsigned short* __restrict__ A,
                                              const unsigned short* __restrict__ B,
                                              const float* __restrict__ bias,
                                              float* __restrict__ O,
                                              unsigned short* __restrict__ Ob,
                                              float* __restrict__ bns, int M) {
    int tid = threadIdx.x;
    int lane = tid & 63, wid = tid >> 6;
    int wm = wid >> 1, wn = wid & 1;
    int bm = blockIdx.x * 128;
    int lr = lane & 15, lk = lane >> 4;
    __shared__ float s1[128], s2[128];
    if (EPI == 1) {
        if (tid < 128) { s1[tid] = 0.f; s2[tid] = 0.f; }
        __syncthreads();
    }
    v4f acc[4][4] = {};
    const unsigned short* Abase = A + (size_t)(bm + wm * 64 + lr) * K + lk * 8;
    const unsigned short* Bbase = B + (size_t)(wn * 64 + lr) * K + lk * 8;
#pragma unroll
    for (int kk = 0; kk < K / 32; kk++) {
        v8s a[4], b[4];
#pragma unroll
        for (int f = 0; f < 4; f++) {
            a[f] = *(const v8s*)(Abase + (size_t)(f * 16) * K + kk * 32);
            b[f] = *(const v8s*)(Bbase + (size_t)(f * 16) * K + kk * 32);
        }
#pragma unroll
        for (int i = 0; i < 4; i++)
#pragma unroll
            for (int j = 0; j < 4; j++)
                acc[i][j] = __builtin_amdgcn_mfma_f32_16x16x32_bf16(a[i], b[j], acc[i][j], 0, 0, 0);
    }
#pragma unroll
    for (int i = 0; i < 4; i++) {
#pragma unroll
        for (int r = 0; r < 4; r++) {
            int row = bm + wm * 64 + i * 16 + lk * 4 + r;
            if (EPI == 0 && row >= M) continue;
#pragma unroll
            for (int j = 0; j < 4; j++) {
                int col = wn * 64 + j * 16 + lr;
                float v = acc[i][j][r];
                if (EPI == 0) {
                    v = fmaxf(v + bias[col], 0.f);
                    O[(size_t)row * HIDD + col] = v;
                    Ob[(size_t)row * HIDD + col] = f2bf(v);
                } else {
                    O[(size_t)row * HIDD + col] = v;
                }
            }
        }
    }
    if (EPI == 1) {
#pragma unroll
        for (int j = 0; j < 4; j++) {
            int col = wn * 64 + j * 16 + lr;
            float ls = 0.f, lq = 0.f;
#pragma unroll
            for (int i = 0; i < 4; i++)
#pragma unroll
                for (int r = 0; r < 4; r++) {
                    float v = acc[i][j][r];
                    ls += v;
                    lq += v * v;
                }
            atomicAdd(&s1[col], ls);
            atomicAdd(&s2[col], lq);
        }
        __syncthreads();
        if (tid < 128) {
            atomicAdd(&bns[tid], s1[tid]);
            atomicAdd(&bns[128 + tid], s2[tid]);
        }
    }
}

// ---------------- CSR build ----------------
__global__ __launch_bounds__(256) void k_deg(const int* __restrict__ ei, int* __restrict__ deg,
                                             int E, int tot) {
    int e = blockIdx.x * 256 + threadIdx.x;
    if (e >= tot) return;
    int dst = (e < E) ? ei[E + e] : (e - E);
    atomicAdd(&deg[dst], 1);
}

__global__ __launch_bounds__(256) void k_scan1(const int* __restrict__ deg,
                                               int* __restrict__ rowptr,
                                               int* __restrict__ partials, int n) {
    int tid = threadIdx.x;
    int i = blockIdx.x * 256 + tid;
    int v = (i < n) ? deg[i] : 0;
    __shared__ int sm[256];
    sm[tid] = v;
    __syncthreads();
    for (int off = 1; off < 256; off <<= 1) {
        int t = (tid >= off) ? sm[tid - off] : 0;
        __syncthreads();
        sm[tid] += t;
        __syncthreads();
    }
    if (i < n) rowptr[i] = sm[tid] - v;  // exclusive within block
    if (tid == 255) partials[blockIdx.x] = sm[255];
}

__global__ __launch_bounds__(256) void k_scan2(int* __restrict__ partials, int nb) {
    int tid = threadIdx.x;
    int v = (tid < nb) ? partials[tid] : 0;
    __shared__ int sm[256];
    sm[tid] = v;
    __syncthreads();
    for (int off = 1; off < 256; off <<= 1) {
        int t = (tid >= off) ? sm[tid - off] : 0;
        __syncthreads();
        sm[tid] += t;
        __syncthreads();
    }
    if (tid < nb) partials[tid] = sm[tid] - v;  // exclusive
}

__global__ __launch_bounds__(256) void k_scan3(const int* __restrict__ deg,
                                               const int* __restrict__ partials,
                                               int* __restrict__ rowptr,
                                               int* __restrict__ cursor, int n) {
    int i = blockIdx.x * 256 + threadIdx.x;
    if (i >= n) return;
    int r = rowptr[i] + partials[blockIdx.x];
    rowptr[i] = r;
    cursor[i] = r;
    if (i == n - 1) rowptr[n] = r + deg[i];
}

__global__ __launch_bounds__(256) void k_scatter(const int* __restrict__ ei, int* __restrict__ cursor,
                                                 int* __restrict__ csr_src, int E, int tot) {
    int e = blockIdx.x * 256 + threadIdx.x;
    if (e >= tot) return;
    int src = (e < E) ? ei[e] : (e - E);
    int dst = (e < E) ? ei[E + e] : (e - E);
    int pos = atomicAdd(&cursor[dst], 1);
    csr_src[pos] = src;
}

// ---------------- layer-0 attention logits from fp32 h ----------------
__global__ __launch_bounds__(256) void k_al0(const float* __restrict__ h,
                                             const float* __restrict__ ws,
                                             const float* __restrict__ wd,
                                             float* __restrict__ al_s, float* __restrict__ al_d,
                                             int n) {
    int wid = threadIdx.x >> 6, lane = threadIdx.x & 63;
    int node = blockIdx.x * 4 + wid;
    if (node >= n) return;
    float2 v = *(const float2*)(h + (size_t)node * HIDD + 2 * lane);
    float s[8];
#pragma unroll
    for (int hh = 0; hh < 4; hh++) {
        float2 w1 = *(const float2*)(ws + hh * HIDD + 2 * lane);
        float2 w2 = *(const float2*)(wd + hh * HIDD + 2 * lane);
        s[hh] = v.x * w1.x + v.y * w1.y;
        s[4 + hh] = v.x * w2.x + v.y * w2.y;
    }
#pragma unroll
    for (int o = 32; o; o >>= 1)
#pragma unroll
        for (int q = 0; q < 8; q++) s[q] += __shfl_xor(s[q], o);
    if (lane == 0) {
        *(float4*)(al_s + (size_t)node * 4) = make_float4(s[0], s[1], s[2], s[3]);
        *(float4*)(al_d + (size_t)node * 4) = make_float4(s[4], s[5], s[6], s[7]);
    }
}

// ---------------- fused per-dst softmax + gather; one wave per node ----------------
// G[n][h*128+k] = sum_e alpha[e,h] * h_bf16[src][k]
__global__ __launch_bounds__(256) void k_attngat(const int* __restrict__ rowptr,
                                                 const int* __restrict__ csr_src,
                                                 const float* __restrict__ al_s,
                                                 const float* __restrict__ al_d,
                                                 const unsigned short* __restrict__ hb,
                                                 unsigned short* __restrict__ g, int n) {
    int wid = threadIdx.x >> 6, lane = threadIdx.x & 63;
    int node = blockIdx.x * 4 + wid;
    if (node >= n) return;
    int start = rowptr[node], end = rowptr[node + 1];
    int deg = end - start;
    const float4* als4 = (const float4*)al_s;
    float4 ad = ((const float4*)al_d)[node];
    const unsigned int* h2 = (const unsigned int*)hb;
    float acc[4][2] = {};

    if (deg <= 64) {
        bool act = lane < deg;
        int src_l = act ? csr_src[start + lane] : 0;
        float e0 = -3.0e38f, e1 = -3.0e38f, e2 = -3.0e38f, e3 = -3.0e38f;
        if (act) {
            float4 as = als4[src_l];
            e0 = lrelu(as.x + ad.x);
            e1 = lrelu(as.y + ad.y);
            e2 = lrelu(as.z + ad.z);
            e3 = lrelu(as.w + ad.w);
        }
        float m0 = e0, m1 = e1, m2 = e2, m3 = e3;
#pragma unroll
        for (int o = 32; o; o >>= 1) {
            m0 = fmaxf(m0, __shfl_xor(m0, o));
            m1 = fmaxf(m1, __shfl_xor(m1, o));
            m2 = fmaxf(m2, __shfl_xor(m2, o));
            m3 = fmaxf(m3, __shfl_xor(m3, o));
        }
        float p0 = act ? expf(e0 - m0) : 0.f;
        float p1 = act ? expf(e1 - m1) : 0.f;
        float p2 = act ? expf(e2 - m2) : 0.f;
        float p3 = act ? expf(e3 - m3) : 0.f;
        float t0 = p0, t1 = p1, t2 = p2, t3 = p3;
#pragma unroll
        for (int o = 32; o; o >>= 1) {
            t0 += __shfl_xor(t0, o);
            t1 += __shfl_xor(t1, o);
            t2 += __shfl_xor(t2, o);
            t3 += __shfl_xor(t3, o);
        }
        float a0 = p0 / (t0 + 1e-16f), a1 = p1 / (t1 + 1e-16f);
        float a2 = p2 / (t2 + 1e-16f), a3 = p3 / (t3 + 1e-16f);
        for (int jj = 0; jj < deg; jj++) {
            int sj = __shfl(src_l, jj);
            float b0 = __shfl(a0, jj), b1 = __shfl(a1, jj);
            float b2 = __shfl(a2, jj), b3 = __shfl(a3, jj);
            unsigned int uu = h2[(size_t)sj * 64 + lane];
            float x0 = bf2f(uu & 0xffff), x1 = bf2f(uu >> 16);
            acc[0][0] += b0 * x0; acc[0][1] += b0 * x1;
            acc[1][0] += b1 * x0; acc[1][1] += b1 * x1;
            acc[2][0] += b2 * x0; acc[2][1] += b2 * x1;
            acc[3][0] += b3 * x0; acc[3][1] += b3 * x1;
        }
    } else {
        float m0 = -3.0e38f, m1 = -3.0e38f, m2 = -3.0e38f, m3 = -3.0e38f;
        for (int j = start + lane; j < end; j += 64) {
            float4 as = als4[csr_src[j]];
            m0 = fmaxf(m0, lrelu(as.x + ad.x));
            m1 = fmaxf(m1, lrelu(as.y + ad.y));
            m2 = fmaxf(m2, lrelu(as.z + ad.z));
            m3 = fmaxf(m3, lrelu(as.w + ad.w));
        }
#pragma unroll
        for (int o = 32; o; o >>= 1) {
            m0 = fmaxf(m0, __shfl_xor(m0, o));
            m1 = fmaxf(m1, __shfl_xor(m1, o));
            m2 = fmaxf(m2, __shfl_xor(m2, o));
            m3 = fmaxf(m3, __shfl_xor(m3, o));
        }
        float t0 = 0.f, t1 = 0.f, t2 = 0.f, t3 = 0.f;
        for (int j = start + lane; j < end; j += 64) {
            float4 as = als4[csr_src[j]];
            t0 += expf(lrelu(as.x + ad.x) - m0);
            t1 += expf(lrelu(as.y + ad.y) - m1);
            t2 += expf(lrelu(as.z + ad.z) - m2);
            t3 += expf(lrelu(as.w + ad.w) - m3);
        }
#pragma unroll
        for (int o = 32; o; o >>= 1) {
            t0 += __shfl_xor(t0, o);
            t1 += __shfl_xor(t1, o);
            t2 += __shfl_xor(t2, o);
            t3 += __shfl_xor(t3, o);
        }
        float i0 = 1.f / (t0 + 1e-16f), i1 = 1.f / (t1 + 1e-16f);
        float i2 = 1.f / (t2 + 1e-16f), i3 = 1.f / (t3 + 1e-16f);
        for (int base = start; base < end; base += 64) {
            int cnt = min(64, end - base);
            bool act = lane < cnt;
            int src_l = act ? csr_src[base + lane] : 0;
            float a0 = 0.f, a1 = 0.f, a2 = 0.f, a3 = 0.f;
            if (act) {
                float4 as = als4[src_l];
                a0 = expf(lrelu(as.x + ad.x) - m0) * i0;
                a1 = expf(lrelu(as.y + ad.y) - m1) * i1;
                a2 = expf(lrelu(as.z + ad.z) - m2) * i2;
                a3 = expf(lrelu(as.w + ad.w) - m3) * i3;
            }
            for (int jj = 0; jj < cnt; jj++) {
                int sj = __shfl(src_l, jj);
                float b0 = __shfl(a0, jj), b1 = __shfl(a1, jj);
                float b2 = __shfl(a2, jj), b3 = __shfl(a3, jj);
                unsigned int uu = h2[(size_t)sj * 64 + lane];
                float x0 = bf2f(uu & 0xffff), x1 = bf2f(uu >> 16);
                acc[0][0] += b0 * x0; acc[0][1] += b0 * x1;
                acc[1][0] += b1 * x0; acc[1][1] += b1 * x1;
                acc[2][0] += b2 * x0; acc[2][1] += b2 * x1;
                acc[3][0] += b3 * x0; acc[3][1] += b3 * x1;
            }
        }
    }
    unsigned int* g2 = (unsigned int*)g;
#pragma unroll
    for (int hh = 0; hh < 4; hh++) {
        unsigned int p = (unsigned int)f2bf(acc[hh][0]) | ((unsigned int)f2bf(acc[hh][1]) << 16);
        g2[(size_t)node * 256 + hh * 64 + lane] = p;
    }
}

// ---------------- fused BN-final + apply + (next-layer al | output head) ----------------
// MODE 0: h += relu(bn(0.25*agg)); write h, hb, al_s/al_d for next layer.
// MODE 1: v = h + relu(bn(0.25*agg)); out = clip(v . Wout + bout).
template <int MODE>
__global__ __launch_bounds__(256) void k_apply(const float* __restrict__ agg,
                                               const float* __restrict__ bns,
                                               const float* __restrict__ gamma,
                                               const float* __restrict__ beta,
                                               float* __restrict__ h,
                                               unsigned short* __restrict__ hb,
                                               const float* __restrict__ ws,
                                               const float* __restrict__ wd,
                                               float* __restrict__ al_s,
                                               float* __restrict__ al_d,
                                               const float* __restrict__ Wout,
                                               const float* __restrict__ bout,
                                               float* __restrict__ out,
                                               float invn, int n) {
    int wid = threadIdx.x >> 6, lane = threadIdx.x & 63;
    int node = blockIdx.x * 4 + wid;
    if (node >= n) return;
    int c0 = 2 * lane, c1 = 2 * lane + 1;
    float2 ag = *(const float2*)(agg + (size_t)node * HIDD + c0);
    float2 ho = *(const float2*)(h + (size_t)node * HIDD + c0);
    // BN constants (agg_used = 0.25*agg_raw folded exactly)
    float mu0 = bns[c0] * invn, mu1 = bns[c1] * invn;
    float va0 = bns[128 + c0] * invn - mu0 * mu0;
    float va1 = bns[128 + c1] * invn - mu1 * mu1;
    float sc0 = gamma[c0] * rsqrtf(0.0625f * va0 + 1e-5f);
    float sc1 = gamma[c1] * rsqrtf(0.0625f * va1 + 1e-5f);
    float v0 = fmaxf((ag.x - mu0) * 0.25f * sc0 + beta[c0], 0.f) + ho.x;
    float v1 = fmaxf((ag.y - mu1) * 0.25f * sc1 + beta[c1], 0.f) + ho.y;
    if (MODE == 0) {
        *(float2*)(h + (size_t)node * HIDD + c0) = make_float2(v0, v1);
        ((unsigned int*)hb)[(size_t)node * 64 + lane] =
            (unsigned int)f2bf(v0) | ((unsigned int)f2bf(v1) << 16);
        float s[8];
#pragma unroll
        for (int hh = 0; hh < 4; hh++) {
            float2 w1 = *(const float2*)(ws + hh * HIDD + c0);
            float2 w2 = *(const float2*)(wd + hh * HIDD + c0);
            s[hh] = v0 * w1.x + v1 * w1.y;
            s[4 + hh] = v0 * w2.x + v1 * w2.y;
        }
#pragma unroll
        for (int o = 32; o; o >>= 1)
#pragma unroll
            for (int q = 0; q < 8; q++) s[q] += __shfl_xor(s[q], o);
        if (lane == 0) {
            *(float4*)(al_s + (size_t)node * 4) = make_float4(s[0], s[1], s[2], s[3]);
            *(float4*)(al_d + (size_t)node * 4) = make_float4(s[4], s[5], s[6], s[7]);
        }
    } else {
        float2 w = *(const float2*)(Wout + c0);
        float p = v0 * w.x + v1 * w.y;
#pragma unroll
        for (int o = 32; o; o >>= 1) p += __shfl_xor(p, o);
        if (lane == 0) {
            float v = p + bout[0];
            out[node] = fminf(fmaxf(v, -10.f), 10.f);
        }
    }
}

extern "C" void kernel_launch(void* const* d_in, const int* in_sizes, int n_in,
                              void* d_out, int out_size, void* d_ws, size_t ws_size,
                              hipStream_t stream) {
    const float* x = (const float*)d_in[0];
    const int* ei = (const int*)d_in[1];
    const float* emb = (const float*)d_in[2];
    const float* Wf = (const float*)d_in[3];
    const float* bf = (const float*)d_in[4];
    const float* Wc = (const float*)d_in[5];
    const float* bc = (const float*)d_in[6];
    const float* Wl = (const float*)d_in[7];
    const float* a_src = (const float*)d_in[8];
    const float* a_dst = (const float*)d_in[9];
    // d_in[10] = bl : cancels in BN mean subtraction
    const float* gamma = (const float*)d_in[11];
    const float* beta = (const float*)d_in[12];
    const float* Wout = (const float*)d_in[13];
    const float* bout = (const float*)d_in[14];
    float* out = (float*)d_out;

    int n = in_sizes[0] / INDIM;  // 50000
    int E = in_sizes[1] / 2;      // 400000
    int tot = E + n;
    int NB = (n + 255) / 256;  // scan blocks

    size_t off = 0;
    auto alloc = [&](size_t bytes) {
        void* p = (char*)d_ws + off;
        off = (off + bytes + 255) & ~(size_t)255;
        return p;
    };
    unsigned short* u = (unsigned short*)alloc((size_t)MPAD * UDIM * 2);
    float* h = (float*)alloc((size_t)MPAD * HIDD * 4);
    unsigned short* hb = (unsigned short*)alloc((size_t)MPAD * HIDD * 2);
    unsigned short* g = (unsigned short*)alloc((size_t)MPAD * 512 * 2);
    float* agg = (float*)alloc((size_t)MPAD * HIDD * 4);
    float* al_s = (float*)alloc((size_t)n * HEADS * 4);
    float* al_d = (float*)alloc((size_t)n * HEADS * 4);
    int* deg = (int*)alloc((size_t)n * 4);
    int* rowptr = (int*)alloc(((size_t)n + 1) * 4);
    int* cursor = (int*)alloc((size_t)n * 4);
    int* csr_src = (int*)alloc((size_t)tot * 4);
    int* partials = (int*)alloc((size_t)NB * 4);
    unsigned short* Vb = (unsigned short*)alloc((size_t)LAYERS * HIDD * 512 * 2);
    unsigned short* Wcb = (unsigned short*)alloc((size_t)HIDD * UDIM * 2);
    float* ws = (float*)alloc((size_t)LAYERS * HEADS * HIDD * 4);
    float* wd = (float*)alloc((size_t)LAYERS * HEADS * HIDD * 4);
    float* bnsums = (float*)alloc(LAYERS * 256 * 4);
    (void)ws_size;

    hipMemsetAsync(deg, 0, (size_t)n * 4, stream);
    hipMemsetAsync(bnsums, 0, LAYERS * 256 * 4, stream);
    if (n < MPAD) {
        hipMemsetAsync(u + (size_t)n * UDIM, 0, (size_t)(MPAD - n) * UDIM * 2, stream);
        hipMemsetAsync(g + (size_t)n * 512, 0, (size_t)(MPAD - n) * 512 * 2, stream);
    }

    // weight precompute
    k_prep_v<<<(LAYERS * HIDD * 512 + 255) / 256, 256, 0, stream>>>(Wl, Vb);
    k_prep_a<<<(LAYERS * HEADS * HIDD + 255) / 256, 256, 0, stream>>>(Wl, a_src, a_dst, ws, wd);
    k_prep_wc<<<(HIDD * UDIM + 255) / 256, 256, 0, stream>>>(Wc, Wcb);

    // CSR build
    k_deg<<<(tot + 255) / 256, 256, 0, stream>>>(ei, deg, E, tot);
    k_scan1<<<NB, 256, 0, stream>>>(deg, rowptr, partials, n);
    k_scan2<<<1, 256, 0, stream>>>(partials, NB);
    k_scan3<<<NB, 256, 0, stream>>>(deg, partials, rowptr, cursor, n);
    k_scatter<<<(tot + 255) / 256, 256, 0, stream>>>(ei, cursor, csr_src, E, tot);

    // encoder
    k_enc<<<(n * EMBD + 255) / 256, 256, 0, stream>>>(x, emb, Wf, bf, u, n);
    k_gemm<UDIM, 0><<<MPAD / 128, 256, 0, stream>>>(u, Wcb, bc, h, hb, nullptr, n);
    k_al0<<<(n + 3) / 4, 256, 0, stream>>>(h, ws, wd, al_s, al_d, n);

    float invn = 1.0f / (float)n;
    for (int l = 0; l < LAYERS; l++) {
        k_attngat<<<(n + 3) / 4, 256, 0, stream>>>(rowptr, csr_src, al_s, al_d, hb, g, n);
        k_gemm<512, 1><<<MPAD / 128, 256, 0, stream>>>(g, Vb + (size_t)l * HIDD * 512, nullptr,
                                                       agg, nullptr, bnsums + l * 256, MPAD);
        if (l < LAYERS - 1)
            k_apply<0><<<(n + 3) / 4, 256, 0, stream>>>(
                agg, bnsums + l * 256, gamma + l * HIDD, beta + l * HIDD, h, hb,
                ws + (size_t)(l + 1) * 512, wd + (size_t)(l + 1) * 512, al_s, al_d,
                nullptr, nullptr, nullptr, invn, n);
        else
            k_apply<1><<<(n + 3) / 4, 256, 0, stream>>>(
                agg, bnsums + l * 256, gamma + l * HIDD, beta + l * HIDD, h, hb,
                nullptr, nullptr, nullptr, nullptr, Wout, bout, out, invn, n);
    }
}